// Round 1
// baseline (6683.351 us; speedup 1.0000x reference)
//
#include <hip/hip_runtime.h>
#include <cstddef>

#define BB 64
#define PP 196
#define ENCD 2048
#define DECD 512
#define ATTD 512
#define EMBD 512
#define VOC 9490
#define TDEC 20
#define FSTR 4608  // F row: [att2 512 | gate 2048 | hh 2048]

__device__ __forceinline__ float sigmoidf_(float x) { return 1.f / (1.f + __expf(-x)); }

// ---------------- mean over P of encoder_out rows (B*ENC rows of 196) -------
__global__ __launch_bounds__(256) void mean_kernel(const float* __restrict__ enc,
                                                   float* __restrict__ mean) {
  int row = blockIdx.x * 4 + (threadIdx.x >> 6);
  int lane = threadIdx.x & 63;
  const float* r = enc + (size_t)row * PP;
  float v = r[lane] + r[lane + 64] + r[lane + 128];
  if (lane < 4) v += r[lane + 192];
#pragma unroll
  for (int off = 32; off; off >>= 1) v += __shfl_down(v, off);
  if (lane == 0) mean[row] = v * (1.f / 196.f);
}

// ---------------- generic 64-row GEMM, k-split with atomicAdd ---------------
// C[64 x N] += A[64 x K_chunk] @ W[.. x N]; block y = k-split index.
__global__ __launch_bounds__(256) void gemm64_atomic(
    const float* __restrict__ A, int lda, const float* __restrict__ W, int ldw,
    float* __restrict__ C, int ldc, const float* __restrict__ bias0,
    const float* __restrict__ bias1, const float* __restrict__ extra,
    long long extra_stride, int kchunk) {
  __shared__ __align__(16) float As[16][68];
  int tid = threadIdx.x;
  int my = tid >> 4, nx = tid & 15;
  int am = tid >> 2, ak = (tid & 3) << 2;
  int n0 = blockIdx.x * 64;
  int k0s = blockIdx.y * kchunk, k0e = k0s + kchunk;
  float acc[4][4] = {};
  for (int k0 = k0s; k0 < k0e; k0 += 16) {
    float4 a4 = *(const float4*)(A + (size_t)am * lda + k0 + ak);
    As[ak + 0][am] = a4.x;
    As[ak + 1][am] = a4.y;
    As[ak + 2][am] = a4.z;
    As[ak + 3][am] = a4.w;
    __syncthreads();
    const float* wp = W + (size_t)k0 * ldw + n0 + (nx << 2);
#pragma unroll
    for (int kk = 0; kk < 16; ++kk) {
      float4 av = *(const float4*)&As[kk][my << 2];
      float4 wv = *(const float4*)(wp + (size_t)kk * ldw);
      acc[0][0] = fmaf(av.x, wv.x, acc[0][0]); acc[0][1] = fmaf(av.x, wv.y, acc[0][1]);
      acc[0][2] = fmaf(av.x, wv.z, acc[0][2]); acc[0][3] = fmaf(av.x, wv.w, acc[0][3]);
      acc[1][0] = fmaf(av.y, wv.x, acc[1][0]); acc[1][1] = fmaf(av.y, wv.y, acc[1][1]);
      acc[1][2] = fmaf(av.y, wv.z, acc[1][2]); acc[1][3] = fmaf(av.y, wv.w, acc[1][3]);
      acc[2][0] = fmaf(av.z, wv.x, acc[2][0]); acc[2][1] = fmaf(av.z, wv.y, acc[2][1]);
      acc[2][2] = fmaf(av.z, wv.z, acc[2][2]); acc[2][3] = fmaf(av.z, wv.w, acc[2][3]);
      acc[3][0] = fmaf(av.w, wv.x, acc[3][0]); acc[3][1] = fmaf(av.w, wv.y, acc[3][1]);
      acc[3][2] = fmaf(av.w, wv.z, acc[3][2]); acc[3][3] = fmaf(av.w, wv.w, acc[3][3]);
    }
    __syncthreads();
  }
  bool first = (blockIdx.y == 0);
#pragma unroll
  for (int i = 0; i < 4; ++i) {
    int row = (my << 2) + i;
#pragma unroll
    for (int j = 0; j < 4; ++j) {
      int col = n0 + (nx << 2) + j;
      float v = acc[i][j];
      if (first) {
        if (bias0) v += bias0[col];
        if (bias1) v += bias1[col];
        if (extra) v += extra[(size_t)row * extra_stride + col];
      }
      atomicAdd(&C[(size_t)row * ldc + col], v);
    }
  }
}

// ---------------- att1 = enc(b,p,e) @ W_enc_att + b_enc_att -----------------
// enc stored [b][e][p]; TN GEMM per batch. grid (a-tiles=8, p-tiles=4, b=64)
__global__ __launch_bounds__(256) void att1_kernel(const float* __restrict__ enc,
                                                   const float* __restrict__ Wea,
                                                   const float* __restrict__ bea,
                                                   float* __restrict__ att1) {
  __shared__ __align__(16) float As[16][68];
  int tid = threadIdx.x;
  int my = tid >> 4, nx = tid & 15;
  int kr = tid >> 4, pg = (tid & 15) << 2;
  int a0 = blockIdx.x * 64;
  int p0 = blockIdx.y * 64;
  int b = blockIdx.z;
  const float* encb = enc + (size_t)b * ENCD * PP;
  float acc[4][4] = {};
  for (int k0 = 0; k0 < ENCD; k0 += 16) {
    float4 v = make_float4(0.f, 0.f, 0.f, 0.f);
    if (p0 + pg <= 192) v = *(const float4*)(encb + (size_t)(k0 + kr) * PP + p0 + pg);
    *(float4*)&As[kr][pg] = v;
    __syncthreads();
    const float* wp = Wea + (size_t)k0 * ATTD + a0 + (nx << 2);
#pragma unroll
    for (int kk = 0; kk < 16; ++kk) {
      float4 av = *(const float4*)&As[kk][my << 2];
      float4 wv = *(const float4*)(wp + (size_t)kk * ATTD);
      acc[0][0] = fmaf(av.x, wv.x, acc[0][0]); acc[0][1] = fmaf(av.x, wv.y, acc[0][1]);
      acc[0][2] = fmaf(av.x, wv.z, acc[0][2]); acc[0][3] = fmaf(av.x, wv.w, acc[0][3]);
      acc[1][0] = fmaf(av.y, wv.x, acc[1][0]); acc[1][1] = fmaf(av.y, wv.y, acc[1][1]);
      acc[1][2] = fmaf(av.y, wv.z, acc[1][2]); acc[1][3] = fmaf(av.y, wv.w, acc[1][3]);
      acc[2][0] = fmaf(av.z, wv.x, acc[2][0]); acc[2][1] = fmaf(av.z, wv.y, acc[2][1]);
      acc[2][2] = fmaf(av.z, wv.z, acc[2][2]); acc[2][3] = fmaf(av.z, wv.w, acc[2][3]);
      acc[3][0] = fmaf(av.w, wv.x, acc[3][0]); acc[3][1] = fmaf(av.w, wv.y, acc[3][1]);
      acc[3][2] = fmaf(av.w, wv.z, acc[3][2]); acc[3][3] = fmaf(av.w, wv.w, acc[3][3]);
    }
    __syncthreads();
  }
#pragma unroll
  for (int i = 0; i < 4; ++i) {
    int p = p0 + (my << 2) + i;
    if (p < PP) {
#pragma unroll
      for (int j = 0; j < 4; ++j) {
        int col = a0 + (nx << 2) + j;
        att1[((size_t)b * PP + p) * ATTD + col] = acc[i][j] + bea[col];
      }
    }
  }
}

// ---------------- segmented h-GEMM: h @ [Wdec|Wfbeta|Whh|Wfc] ---------------
struct SegArgs {
  int nseg;
  int blk_off[5];
  const float* W[4];
  const float* bias[4];
  float* out[4];
  long long ostride[4];
  int N[4];
  int act[4];  // 0 none, 1 sigmoid
};

__global__ __launch_bounds__(256) void gemm64_seg(const float* __restrict__ A, int K,
                                                  SegArgs sa) {
  int bx = blockIdx.x;
  int s = 0;
  while (s + 1 < sa.nseg && bx >= sa.blk_off[s + 1]) ++s;
  const float* W = sa.W[s];
  int N = sa.N[s];
  int n0 = (bx - sa.blk_off[s]) * 64;

  __shared__ __align__(16) float As[16][68];
  int tid = threadIdx.x;
  int my = tid >> 4, nx = tid & 15;
  int am = tid >> 2, ak = (tid & 3) << 2;
  float acc[4][4] = {};
  for (int k0 = 0; k0 < K; k0 += 16) {
    float4 a4 = *(const float4*)(A + (size_t)am * K + k0 + ak);
    As[ak + 0][am] = a4.x;
    As[ak + 1][am] = a4.y;
    As[ak + 2][am] = a4.z;
    As[ak + 3][am] = a4.w;
    __syncthreads();
    int colb = n0 + (nx << 2);
#pragma unroll
    for (int kk = 0; kk < 16; ++kk) {
      float4 av = *(const float4*)&As[kk][my << 2];
      const float* wrow = W + (size_t)(k0 + kk) * N;
      float4 wv;
      if (colb + 3 < N) {
        wv = *(const float4*)(wrow + colb);
      } else {
        wv.x = (colb + 0 < N) ? wrow[colb + 0] : 0.f;
        wv.y = (colb + 1 < N) ? wrow[colb + 1] : 0.f;
        wv.z = (colb + 2 < N) ? wrow[colb + 2] : 0.f;
        wv.w = (colb + 3 < N) ? wrow[colb + 3] : 0.f;
      }
      acc[0][0] = fmaf(av.x, wv.x, acc[0][0]); acc[0][1] = fmaf(av.x, wv.y, acc[0][1]);
      acc[0][2] = fmaf(av.x, wv.z, acc[0][2]); acc[0][3] = fmaf(av.x, wv.w, acc[0][3]);
      acc[1][0] = fmaf(av.y, wv.x, acc[1][0]); acc[1][1] = fmaf(av.y, wv.y, acc[1][1]);
      acc[1][2] = fmaf(av.y, wv.z, acc[1][2]); acc[1][3] = fmaf(av.y, wv.w, acc[1][3]);
      acc[2][0] = fmaf(av.z, wv.x, acc[2][0]); acc[2][1] = fmaf(av.z, wv.y, acc[2][1]);
      acc[2][2] = fmaf(av.z, wv.z, acc[2][2]); acc[2][3] = fmaf(av.z, wv.w, acc[2][3]);
      acc[3][0] = fmaf(av.w, wv.x, acc[3][0]); acc[3][1] = fmaf(av.w, wv.y, acc[3][1]);
      acc[3][2] = fmaf(av.w, wv.z, acc[3][2]); acc[3][3] = fmaf(av.w, wv.w, acc[3][3]);
    }
    __syncthreads();
  }
  const float* bias = sa.bias[s];
  float* out = sa.out[s];
  long long ostr = sa.ostride[s];
  int actv = sa.act[s];
#pragma unroll
  for (int i = 0; i < 4; ++i) {
    int row = (my << 2) + i;
#pragma unroll
    for (int j = 0; j < 4; ++j) {
      int col = n0 + (nx << 2) + j;
      if (col < N) {
        float v = acc[i][j];
        if (bias) v += bias[col];
        if (actv == 1) v = sigmoidf_(v);
        out[(size_t)row * ostr + col] = v;
      }
    }
  }
}

// ---------- attention score + softmax + alpha out + embedding gather -------
__global__ __launch_bounds__(256) void attn_kernel(
    const float* __restrict__ att1, const float* __restrict__ F,
    const float* __restrict__ W_full, const int* __restrict__ captions,
    const float* __restrict__ embedding, float* __restrict__ alpha_buf,
    float* __restrict__ alphas_out, float* __restrict__ lstm_in, int t) {
  int b = blockIdx.x, tid = threadIdx.x;
  __shared__ __align__(16) float att2s[ATTD];
  __shared__ __align__(16) float wf[ATTD];
  __shared__ float sc[256];
  __shared__ float red[256];
  att2s[tid] = F[(size_t)b * FSTR + tid];
  att2s[tid + 256] = F[(size_t)b * FSTR + tid + 256];
  wf[tid] = W_full[tid];
  wf[tid + 256] = W_full[tid + 256];
  __syncthreads();
  float s = -1e30f;
  if (tid < PP) {
    const float4* row = (const float4*)(att1 + ((size_t)b * PP + tid) * ATTD);
    const float4* a2 = (const float4*)att2s;
    const float4* w4 = (const float4*)wf;
    float acc = 0.f;
#pragma unroll 8
    for (int i = 0; i < ATTD / 4; ++i) {
      float4 v = row[i], a = a2[i], w = w4[i];
      acc = fmaf(fmaxf(v.x + a.x, 0.f), w.x, acc);
      acc = fmaf(fmaxf(v.y + a.y, 0.f), w.y, acc);
      acc = fmaf(fmaxf(v.z + a.z, 0.f), w.z, acc);
      acc = fmaf(fmaxf(v.w + a.w, 0.f), w.w, acc);
    }
    s = acc;
  }
  sc[tid] = s;
  __syncthreads();
  for (int off = 128; off; off >>= 1) {
    if (tid < off) sc[tid] = fmaxf(sc[tid], sc[tid + off]);
    __syncthreads();
  }
  float m = sc[0];
  float e = (tid < PP) ? __expf(s - m) : 0.f;
  red[tid] = e;
  __syncthreads();
  for (int off = 128; off; off >>= 1) {
    if (tid < off) red[tid] += red[tid + off];
    __syncthreads();
  }
  float a = e * (1.f / red[0]);
  if (tid < PP) {
    alpha_buf[b * PP + tid] = a;
    alphas_out[(size_t)b * (TDEC * PP) + tid] = a;
  }
  // embedding gather -> lstm_in[:, 0:512)
  int tok = captions[b * 21 + t];
  lstm_in[(size_t)b * (EMBD + ENCD) + tid] = embedding[(size_t)tok * EMBD + tid];
  lstm_in[(size_t)b * (EMBD + ENCD) + tid + 256] = embedding[(size_t)tok * EMBD + tid + 256];
}

// ---------------- awe[b,e] = gate[b,e] * sum_p enc[b,e,p]*alpha[b,p] --------
__global__ __launch_bounds__(256) void awe_kernel(const float* __restrict__ enc,
                                                  const float* __restrict__ alpha_buf,
                                                  const float* __restrict__ F,
                                                  float* __restrict__ lstm_in) {
  int b = blockIdx.y;
  int e = blockIdx.x * 256 + threadIdx.x;
  __shared__ __align__(16) float al[PP];
  if (threadIdx.x < PP) al[threadIdx.x] = alpha_buf[b * PP + threadIdx.x];
  __syncthreads();
  const float4* row = (const float4*)(enc + ((size_t)b * ENCD + e) * PP);
  const float4* al4 = (const float4*)al;
  float acc = 0.f;
#pragma unroll 7
  for (int i = 0; i < PP / 4; ++i) {
    float4 v = row[i], a = al4[i];
    acc = fmaf(v.x, a.x, acc);
    acc = fmaf(v.y, a.y, acc);
    acc = fmaf(v.z, a.z, acc);
    acc = fmaf(v.w, a.w, acc);
  }
  float gate = F[(size_t)b * FSTR + ATTD + e];
  lstm_in[(size_t)b * (EMBD + ENCD) + EMBD + e] = gate * acc;
}

// ---------------- LSTM pointwise; also re-zeros gates for next step ---------
__global__ __launch_bounds__(256) void lstm_kernel(float* __restrict__ gates,
                                                   float* __restrict__ c,
                                                   float* __restrict__ h) {
  int idx = blockIdx.x * 256 + threadIdx.x;  // 0..32767
  int b = idx >> 9, d = idx & 511;
  float* g = gates + (size_t)b * 2048;
  float gi = g[d], gf = g[d + 512], gg = g[d + 1024], go = g[d + 1536];
  g[d] = 0.f;
  g[d + 512] = 0.f;
  g[d + 1024] = 0.f;
  g[d + 1536] = 0.f;
  float iv = sigmoidf_(gi);
  float fv = sigmoidf_(gf);
  float ov = sigmoidf_(go);
  float gv = tanhf(gg);
  float cn = fv * c[idx] + iv * gv;
  c[idx] = cn;
  h[idx] = ov * tanhf(cn);
}

extern "C" void kernel_launch(void* const* d_in, const int* in_sizes, int n_in,
                              void* d_out, int out_size, void* d_ws, size_t ws_size,
                              hipStream_t stream) {
  const float* enc = (const float*)d_in[0];
  const int* captions = (const int*)d_in[1];
  const float* W_enc_att = (const float*)d_in[2];
  const float* b_enc_att = (const float*)d_in[3];
  const float* W_dec_att = (const float*)d_in[4];
  const float* b_dec_att = (const float*)d_in[5];
  const float* W_full = (const float*)d_in[6];
  // d_in[7] = b_full_att : softmax-invariant constant, unused
  const float* embedding = (const float*)d_in[8];
  const float* W_ih = (const float*)d_in[9];
  const float* W_hh = (const float*)d_in[10];
  const float* b_ih = (const float*)d_in[11];
  const float* b_hh = (const float*)d_in[12];
  const float* W_init_h = (const float*)d_in[13];
  const float* b_init_h = (const float*)d_in[14];
  const float* W_init_c = (const float*)d_in[15];
  const float* b_init_c = (const float*)d_in[16];
  const float* W_f_beta = (const float*)d_in[17];
  const float* b_f_beta = (const float*)d_in[18];
  const float* W_fc = (const float*)d_in[19];
  const float* b_fc = (const float*)d_in[20];

  float* out = (float*)d_out;
  float* preds = out;                                    // 64*20*9490
  float* alphas = out + (size_t)BB * TDEC * VOC;         // 64*20*196

  float* ws = (float*)d_ws;
  float* mean = ws;                     // 131072
  float* h = mean + BB * ENCD;          // 32768
  float* c = h + BB * DECD;             // 32768
  float* F = c + BB * DECD;             // 64*4608 = 294912
  float* att1 = F + BB * FSTR;          // 64*196*512 = 6422528
  float* alpha = att1 + (size_t)BB * PP * ATTD;  // 12544
  float* lstm_in = alpha + BB * PP;     // 64*2560 = 163840
  float* gates = lstm_in + BB * (EMBD + ENCD);   // 64*2048 = 131072

  hipMemsetAsync(h, 0, (size_t)BB * DECD * 4, stream);
  hipMemsetAsync(c, 0, (size_t)BB * DECD * 4, stream);
  hipMemsetAsync(gates, 0, (size_t)BB * 2048 * 4, stream);

  mean_kernel<<<BB * ENCD / 4, 256, 0, stream>>>(enc, mean);
  gemm64_atomic<<<dim3(DECD / 64, 4), 256, 0, stream>>>(mean, ENCD, W_init_h, DECD, h,
                                                        DECD, b_init_h, nullptr, nullptr,
                                                        0, 512);
  gemm64_atomic<<<dim3(DECD / 64, 4), 256, 0, stream>>>(mean, ENCD, W_init_c, DECD, c,
                                                        DECD, b_init_c, nullptr, nullptr,
                                                        0, 512);
  att1_kernel<<<dim3(ATTD / 64, 4, BB), 256, 0, stream>>>(enc, W_enc_att, b_enc_att,
                                                          att1);

  for (int t = 0; t <= TDEC; ++t) {
    SegArgs sa{};
    int nb = 0, s = 0;
    if (t < TDEC) {
      sa.blk_off[s] = nb; sa.W[s] = W_dec_att; sa.bias[s] = b_dec_att;
      sa.out[s] = F; sa.ostride[s] = FSTR; sa.N[s] = ATTD; sa.act[s] = 0;
      nb += ATTD / 64; ++s;
      sa.blk_off[s] = nb; sa.W[s] = W_f_beta; sa.bias[s] = b_f_beta;
      sa.out[s] = F + ATTD; sa.ostride[s] = FSTR; sa.N[s] = ENCD; sa.act[s] = 1;
      nb += ENCD / 64; ++s;
      sa.blk_off[s] = nb; sa.W[s] = W_hh; sa.bias[s] = nullptr;
      sa.out[s] = F + ATTD + ENCD; sa.ostride[s] = FSTR; sa.N[s] = ENCD; sa.act[s] = 0;
      nb += ENCD / 64; ++s;
    }
    if (t > 0) {
      sa.blk_off[s] = nb; sa.W[s] = W_fc; sa.bias[s] = b_fc;
      sa.out[s] = preds + (size_t)(t - 1) * VOC;
      sa.ostride[s] = (long long)TDEC * VOC; sa.N[s] = VOC; sa.act[s] = 0;
      nb += (VOC + 63) / 64; ++s;
    }
    sa.nseg = s;
    sa.blk_off[s] = nb;
    gemm64_seg<<<nb, 256, 0, stream>>>(h, DECD, sa);
    if (t == TDEC) break;

    attn_kernel<<<BB, 256, 0, stream>>>(att1, F, W_full, captions, embedding, alpha,
                                        alphas + (size_t)t * PP, lstm_in, t);
    awe_kernel<<<dim3(ENCD / 256, BB), 256, 0, stream>>>(enc, alpha, F, lstm_in);
    gemm64_atomic<<<dim3(2048 / 64, 5), 256, 0, stream>>>(
        lstm_in, EMBD + ENCD, W_ih, 2048, gates, 2048, b_ih, b_hh, F + ATTD + ENCD,
        FSTR, 512);
    lstm_kernel<<<BB * DECD / 256, 256, 0, stream>>>(gates, c, h);
  }
}

// Round 3
// 4088.728 us; speedup vs baseline: 1.6346x; 1.6346x over previous
//
#include <hip/hip_runtime.h>
#include <cstddef>

#define BB 64
#define PP 196
#define ENCD 2048
#define DECD 512
#define ATTD 512
#define EMBD 512
#define VOC 9490
#define TDEC 20
#define F2STR 2560  // F2 row: [att2 512 | gate 2048]

__device__ __forceinline__ float sigmoidf_(float x) { return 1.f / (1.f + __expf(-x)); }

// ---------------- mean over P of encoder_out rows (B*ENC rows of 196) -------
__global__ __launch_bounds__(256) void mean_kernel(const float* __restrict__ enc,
                                                   float* __restrict__ mean) {
  int row = blockIdx.x * 4 + (threadIdx.x >> 6);
  int lane = threadIdx.x & 63;
  const float* r = enc + (size_t)row * PP;
  float v = r[lane] + r[lane + 64] + r[lane + 128];
  if (lane < 4) v += r[lane + 192];
#pragma unroll
  for (int off = 32; off; off >>= 1) v += __shfl_down(v, off);
  if (lane == 0) mean[row] = v * (1.f / 196.f);
}

// ---------------- 64-row x 64-col GEMM, k-split atomic (init h0/c0) ---------
__global__ __launch_bounds__(256) void gemm64_atomic(
    const float* __restrict__ A, int lda, const float* __restrict__ W, int ldw,
    float* __restrict__ C, int ldc, const float* __restrict__ bias0, int kchunk) {
  __shared__ __align__(16) float As[16][68];
  int tid = threadIdx.x;
  int my = tid >> 4, nx = tid & 15;
  int am = tid >> 2, ak = (tid & 3) << 2;
  int n0 = blockIdx.x * 64;
  int k0s = blockIdx.y * kchunk, k0e = k0s + kchunk;
  float acc[4][4] = {};
  for (int k0 = k0s; k0 < k0e; k0 += 16) {
    float4 a4 = *(const float4*)(A + (size_t)am * lda + k0 + ak);
    As[ak + 0][am] = a4.x;
    As[ak + 1][am] = a4.y;
    As[ak + 2][am] = a4.z;
    As[ak + 3][am] = a4.w;
    __syncthreads();
    const float* wp = W + (size_t)k0 * ldw + n0 + (nx << 2);
#pragma unroll
    for (int kk = 0; kk < 16; ++kk) {
      float4 av = *(const float4*)&As[kk][my << 2];
      float4 wv = *(const float4*)(wp + (size_t)kk * ldw);
      acc[0][0] = fmaf(av.x, wv.x, acc[0][0]); acc[0][1] = fmaf(av.x, wv.y, acc[0][1]);
      acc[0][2] = fmaf(av.x, wv.z, acc[0][2]); acc[0][3] = fmaf(av.x, wv.w, acc[0][3]);
      acc[1][0] = fmaf(av.y, wv.x, acc[1][0]); acc[1][1] = fmaf(av.y, wv.y, acc[1][1]);
      acc[1][2] = fmaf(av.y, wv.z, acc[1][2]); acc[1][3] = fmaf(av.y, wv.w, acc[1][3]);
      acc[2][0] = fmaf(av.z, wv.x, acc[2][0]); acc[2][1] = fmaf(av.z, wv.y, acc[2][1]);
      acc[2][2] = fmaf(av.z, wv.z, acc[2][2]); acc[2][3] = fmaf(av.z, wv.w, acc[2][3]);
      acc[3][0] = fmaf(av.w, wv.x, acc[3][0]); acc[3][1] = fmaf(av.w, wv.y, acc[3][1]);
      acc[3][2] = fmaf(av.w, wv.z, acc[3][2]); acc[3][3] = fmaf(av.w, wv.w, acc[3][3]);
    }
    __syncthreads();
  }
  bool first = (blockIdx.y == 0);
#pragma unroll
  for (int i = 0; i < 4; ++i) {
    int row = (my << 2) + i;
#pragma unroll
    for (int j = 0; j < 4; ++j) {
      int col = n0 + (nx << 2) + j;
      float v = acc[i][j];
      if (first && bias0) v += bias0[col];
      atomicAdd(&C[(size_t)row * ldc + col], v);
    }
  }
}

// ---------------- att1 = enc(b,p,e) @ W_enc_att + b_enc_att -----------------
__global__ __launch_bounds__(256) void att1_kernel(const float* __restrict__ enc,
                                                   const float* __restrict__ Wea,
                                                   const float* __restrict__ bea,
                                                   float* __restrict__ att1) {
  __shared__ __align__(16) float As[16][68];
  int tid = threadIdx.x;
  int my = tid >> 4, nx = tid & 15;
  int kr = tid >> 4, pg = (tid & 15) << 2;
  int a0 = blockIdx.x * 64;
  int p0 = blockIdx.y * 64;
  int b = blockIdx.z;
  const float* encb = enc + (size_t)b * ENCD * PP;
  float acc[4][4] = {};
  for (int k0 = 0; k0 < ENCD; k0 += 16) {
    float4 v = make_float4(0.f, 0.f, 0.f, 0.f);
    if (p0 + pg <= 192) v = *(const float4*)(encb + (size_t)(k0 + kr) * PP + p0 + pg);
    *(float4*)&As[kr][pg] = v;
    __syncthreads();
    const float* wp = Wea + (size_t)k0 * ATTD + a0 + (nx << 2);
#pragma unroll
    for (int kk = 0; kk < 16; ++kk) {
      float4 av = *(const float4*)&As[kk][my << 2];
      float4 wv = *(const float4*)(wp + (size_t)kk * ATTD);
      acc[0][0] = fmaf(av.x, wv.x, acc[0][0]); acc[0][1] = fmaf(av.x, wv.y, acc[0][1]);
      acc[0][2] = fmaf(av.x, wv.z, acc[0][2]); acc[0][3] = fmaf(av.x, wv.w, acc[0][3]);
      acc[1][0] = fmaf(av.y, wv.x, acc[1][0]); acc[1][1] = fmaf(av.y, wv.y, acc[1][1]);
      acc[1][2] = fmaf(av.y, wv.z, acc[1][2]); acc[1][3] = fmaf(av.y, wv.w, acc[1][3]);
      acc[2][0] = fmaf(av.z, wv.x, acc[2][0]); acc[2][1] = fmaf(av.z, wv.y, acc[2][1]);
      acc[2][2] = fmaf(av.z, wv.z, acc[2][2]); acc[2][3] = fmaf(av.z, wv.w, acc[2][3]);
      acc[3][0] = fmaf(av.w, wv.x, acc[3][0]); acc[3][1] = fmaf(av.w, wv.y, acc[3][1]);
      acc[3][2] = fmaf(av.w, wv.z, acc[3][2]); acc[3][3] = fmaf(av.w, wv.w, acc[3][3]);
    }
    __syncthreads();
  }
#pragma unroll
  for (int i = 0; i < 4; ++i) {
    int p = p0 + (my << 2) + i;
    if (p < PP) {
#pragma unroll
      for (int j = 0; j < 4; ++j) {
        int col = a0 + (nx << 2) + j;
        att1[((size_t)b * PP + p) * ATTD + col] = acc[i][j] + bea[col];
      }
    }
  }
}

// -- per-step h-GEMM: h@[Wdec -> F2 | Wfbeta(sigma) -> F2 | Whh+bih+bhh -> gates]
__global__ __launch_bounds__(256) void hgemm_step(
    const float* __restrict__ hprev, const float* __restrict__ Wdec,
    const float* __restrict__ bdec, const float* __restrict__ Wfb,
    const float* __restrict__ bfb, const float* __restrict__ Whh,
    const float* __restrict__ b_ih, const float* __restrict__ b_hh,
    float* __restrict__ F2, float* __restrict__ gates) {
  int cg0 = blockIdx.x * 32;  // [0, 4608)
  const float* W;
  const float* bias;
  const float* bias2 = nullptr;
  float* outp;
  int ostr, wcol, act, ldw, ocol;
  if (cg0 < ATTD) {
    W = Wdec; bias = bdec; wcol = cg0; act = 0; ldw = ATTD;
    outp = F2; ostr = F2STR; ocol = cg0;
  } else if (cg0 < ATTD + ENCD) {
    W = Wfb; bias = bfb; wcol = cg0 - ATTD; act = 1; ldw = ENCD;
    outp = F2; ostr = F2STR; ocol = cg0;
  } else {
    W = Whh; bias = b_ih; bias2 = b_hh; wcol = cg0 - (ATTD + ENCD); act = 0;
    ldw = 4 * DECD; outp = gates; ostr = 4 * DECD; ocol = wcol;
  }
  __shared__ __align__(16) float As[16][68];
  int tid = threadIdx.x;
  int my = tid >> 3, nx = tid & 7;  // 2 rows x 4 cols per thread
  int am = tid >> 2, ak = (tid & 3) << 2;
  float acc[2][4] = {};
  for (int k0 = 0; k0 < DECD; k0 += 16) {
    float4 a4 = *(const float4*)(hprev + (size_t)am * DECD + k0 + ak);
    As[ak + 0][am] = a4.x;
    As[ak + 1][am] = a4.y;
    As[ak + 2][am] = a4.z;
    As[ak + 3][am] = a4.w;
    __syncthreads();
    const float* wp = W + (size_t)k0 * ldw + wcol + (nx << 2);
#pragma unroll
    for (int kk = 0; kk < 16; ++kk) {
      float2 av = *(const float2*)&As[kk][my << 1];
      float4 wv = *(const float4*)(wp + (size_t)kk * ldw);
      acc[0][0] = fmaf(av.x, wv.x, acc[0][0]); acc[0][1] = fmaf(av.x, wv.y, acc[0][1]);
      acc[0][2] = fmaf(av.x, wv.z, acc[0][2]); acc[0][3] = fmaf(av.x, wv.w, acc[0][3]);
      acc[1][0] = fmaf(av.y, wv.x, acc[1][0]); acc[1][1] = fmaf(av.y, wv.y, acc[1][1]);
      acc[1][2] = fmaf(av.y, wv.z, acc[1][2]); acc[1][3] = fmaf(av.y, wv.w, acc[1][3]);
    }
    __syncthreads();
  }
#pragma unroll
  for (int i = 0; i < 2; ++i) {
    int row = (my << 1) + i;
#pragma unroll
    for (int j = 0; j < 4; ++j) {
      int cl = (nx << 2) + j;
      float v = acc[i][j] + bias[wcol + cl];
      if (bias2) v += bias2[wcol + cl];
      if (act) v = sigmoidf_(v);
      outp[(size_t)row * ostr + ocol + cl] = v;
    }
  }
}

// -------- score[b,p] = sum_a relu(att1+att2)*wf : one wave per (b,p) --------
__global__ __launch_bounds__(256) void score_kernel(const float* __restrict__ att1,
                                                    const float* __restrict__ F2,
                                                    const float* __restrict__ W_full,
                                                    float* __restrict__ scores) {
  int w = blockIdx.x * 4 + (threadIdx.x >> 6);  // [0, 12544)
  int lane = threadIdx.x & 63;
  int b = w / PP, p = w - b * PP;
  const float4* row = (const float4*)(att1 + ((size_t)b * PP + p) * ATTD) + (lane << 1);
  const float4* a2 = (const float4*)(F2 + (size_t)b * F2STR) + (lane << 1);
  const float4* w4 = (const float4*)W_full + (lane << 1);
  float acc = 0.f;
#pragma unroll
  for (int i = 0; i < 2; ++i) {
    float4 v = row[i], a = a2[i], wf = w4[i];
    acc = fmaf(fmaxf(v.x + a.x, 0.f), wf.x, acc);
    acc = fmaf(fmaxf(v.y + a.y, 0.f), wf.y, acc);
    acc = fmaf(fmaxf(v.z + a.z, 0.f), wf.z, acc);
    acc = fmaf(fmaxf(v.w + a.w, 0.f), wf.w, acc);
  }
#pragma unroll
  for (int off = 32; off; off >>= 1) acc += __shfl_down(acc, off);
  if (lane == 0) scores[b * PP + p] = acc;
}

// -------- softmax(196) per block + gated awe for a 256-wide e-slice ---------
__global__ __launch_bounds__(256) void awe_softmax_kernel(
    const float* __restrict__ scores, const float* __restrict__ F2,
    const float* __restrict__ enc, float* __restrict__ alphas_out,
    float* __restrict__ lstm_in, int t) {
  int b = blockIdx.y, et = blockIdx.x, tid = threadIdx.x;
  __shared__ __align__(16) float al[256];
  __shared__ float sc[256];
  __shared__ float red[256];
  float s = (tid < PP) ? scores[b * PP + tid] : -1e30f;
  sc[tid] = s;
  __syncthreads();
  for (int off = 128; off; off >>= 1) {
    if (tid < off) sc[tid] = fmaxf(sc[tid], sc[tid + off]);
    __syncthreads();
  }
  float e = (tid < PP) ? __expf(s - sc[0]) : 0.f;
  red[tid] = e;
  __syncthreads();
  for (int off = 128; off; off >>= 1) {
    if (tid < off) red[tid] += red[tid + off];
    __syncthreads();
  }
  float a = e * (1.f / red[0]);
  al[tid] = a;
  if (et == 0 && tid < PP)
    alphas_out[(size_t)b * (TDEC * PP) + (size_t)t * PP + tid] = a;
  __syncthreads();
  int e0 = et * 256 + tid;
  const float4* row = (const float4*)(enc + ((size_t)b * ENCD + e0) * PP);
  const float4* al4 = (const float4*)al;
  float acc = 0.f;
#pragma unroll 7
  for (int i = 0; i < PP / 4; ++i) {
    float4 v = row[i], aa = al4[i];
    acc = fmaf(v.x, aa.x, acc);
    acc = fmaf(v.y, aa.y, acc);
    acc = fmaf(v.z, aa.z, acc);
    acc = fmaf(v.w, aa.w, acc);
  }
  float gate = F2[(size_t)b * F2STR + ATTD + e0];
  lstm_in[(size_t)b * (EMBD + ENCD) + EMBD + e0] = gate * acc;
}

// -------- gates += lstm_in @ W_ih  (k-split atomic; biases+hh already there) -
__global__ __launch_bounds__(256) void gates_gemm(const float* __restrict__ A,
                                                  const float* __restrict__ W_ih,
                                                  float* __restrict__ gates) {
  const int K = EMBD + ENCD, N = 4 * DECD, kchunk = 512;
  __shared__ __align__(16) float As[16][68];
  int tid = threadIdx.x;
  int my = tid >> 3, nx = tid & 7;
  int am = tid >> 2, ak = (tid & 3) << 2;
  int n0 = blockIdx.x * 32;
  int k0s = blockIdx.y * kchunk, k0e = k0s + kchunk;
  float acc[2][4] = {};
  for (int k0 = k0s; k0 < k0e; k0 += 16) {
    float4 a4 = *(const float4*)(A + (size_t)am * K + k0 + ak);
    As[ak + 0][am] = a4.x;
    As[ak + 1][am] = a4.y;
    As[ak + 2][am] = a4.z;
    As[ak + 3][am] = a4.w;
    __syncthreads();
    const float* wp = W_ih + (size_t)k0 * N + n0 + (nx << 2);
#pragma unroll
    for (int kk = 0; kk < 16; ++kk) {
      float2 av = *(const float2*)&As[kk][my << 1];
      float4 wv = *(const float4*)(wp + (size_t)kk * N);
      acc[0][0] = fmaf(av.x, wv.x, acc[0][0]); acc[0][1] = fmaf(av.x, wv.y, acc[0][1]);
      acc[0][2] = fmaf(av.x, wv.z, acc[0][2]); acc[0][3] = fmaf(av.x, wv.w, acc[0][3]);
      acc[1][0] = fmaf(av.y, wv.x, acc[1][0]); acc[1][1] = fmaf(av.y, wv.y, acc[1][1]);
      acc[1][2] = fmaf(av.y, wv.z, acc[1][2]); acc[1][3] = fmaf(av.y, wv.w, acc[1][3]);
    }
    __syncthreads();
  }
#pragma unroll
  for (int i = 0; i < 2; ++i) {
    int row = (my << 1) + i;
#pragma unroll
    for (int j = 0; j < 4; ++j) {
      int col = n0 + (nx << 2) + j;
      atomicAdd(&gates[(size_t)row * N + col], acc[i][j]);
    }
  }
}

// ---- LSTM pointwise -> h into Hbuf slot; gathers next-step embedding -------
__global__ __launch_bounds__(256) void lstm_kernel(const float* __restrict__ gates,
                                                   float* __restrict__ c,
                                                   float* __restrict__ hout,
                                                   const int* __restrict__ captions,
                                                   const float* __restrict__ embedding,
                                                   float* __restrict__ lstm_in, int tn) {
  int idx = blockIdx.x * 256 + threadIdx.x;  // 0..32767
  int b = idx >> 9, d = idx & 511;
  const float* g = gates + (size_t)b * 2048;
  float gi = g[d], gf = g[d + 512], gg = g[d + 1024], go = g[d + 1536];
  float iv = sigmoidf_(gi);
  float fv = sigmoidf_(gf);
  float ov = sigmoidf_(go);
  float gv = tanhf(gg);
  float cn = fv * c[idx] + iv * gv;
  c[idx] = cn;
  hout[idx] = ov * tanhf(cn);
  int tok = captions[b * 21 + tn];
  lstm_in[(size_t)b * (EMBD + ENCD) + d] = embedding[(size_t)tok * EMBD + d];
}

// ---------------- t=0 embedding gather --------------------------------------
__global__ __launch_bounds__(256) void emb0_kernel(const int* __restrict__ captions,
                                                   const float* __restrict__ embedding,
                                                   float* __restrict__ lstm_in) {
  int idx = blockIdx.x * 256 + threadIdx.x;
  int b = idx >> 9, d = idx & 511;
  int tok = captions[b * 21];
  lstm_in[(size_t)b * (EMBD + ENCD) + d] = embedding[(size_t)tok * EMBD + d];
}

// ---------------- final preds = Hfc(1280x512) @ W_fc + b_fc -----------------
__global__ __launch_bounds__(256) void fc_kernel(const float* __restrict__ Hfc,
                                                 const float* __restrict__ W_fc,
                                                 const float* __restrict__ b_fc,
                                                 float* __restrict__ preds) {
  __shared__ __align__(16) float As[16][68];
  int tid = threadIdx.x;
  int my = tid >> 4, nx = tid & 15;
  int am = tid >> 2, ak = (tid & 3) << 2;
  int n0 = blockIdx.x * 64;
  int r0 = blockIdx.y * 64;
  const float* A = Hfc + (size_t)r0 * DECD;
  float acc[4][4] = {};
  for (int k0 = 0; k0 < DECD; k0 += 16) {
    float4 a4 = *(const float4*)(A + (size_t)am * DECD + k0 + ak);
    As[ak + 0][am] = a4.x;
    As[ak + 1][am] = a4.y;
    As[ak + 2][am] = a4.z;
    As[ak + 3][am] = a4.w;
    __syncthreads();
    int colb = n0 + (nx << 2);
#pragma unroll
    for (int kk = 0; kk < 16; ++kk) {
      float4 av = *(const float4*)&As[kk][my << 2];
      const float* wrow = W_fc + (size_t)(k0 + kk) * VOC;
      float4 wv;
      if (colb + 3 < VOC) {
        wv = *(const float4*)(wrow + colb);
      } else {
        wv.x = (colb + 0 < VOC) ? wrow[colb + 0] : 0.f;
        wv.y = (colb + 1 < VOC) ? wrow[colb + 1] : 0.f;
        wv.z = (colb + 2 < VOC) ? wrow[colb + 2] : 0.f;
        wv.w = (colb + 3 < VOC) ? wrow[colb + 3] : 0.f;
      }
      acc[0][0] = fmaf(av.x, wv.x, acc[0][0]); acc[0][1] = fmaf(av.x, wv.y, acc[0][1]);
      acc[0][2] = fmaf(av.x, wv.z, acc[0][2]); acc[0][3] = fmaf(av.x, wv.w, acc[0][3]);
      acc[1][0] = fmaf(av.y, wv.x, acc[1][0]); acc[1][1] = fmaf(av.y, wv.y, acc[1][1]);
      acc[1][2] = fmaf(av.y, wv.z, acc[1][2]); acc[1][3] = fmaf(av.y, wv.w, acc[1][3]);
      acc[2][0] = fmaf(av.z, wv.x, acc[2][0]); acc[2][1] = fmaf(av.z, wv.y, acc[2][1]);
      acc[2][2] = fmaf(av.z, wv.z, acc[2][2]); acc[2][3] = fmaf(av.z, wv.w, acc[2][3]);
      acc[3][0] = fmaf(av.w, wv.x, acc[3][0]); acc[3][1] = fmaf(av.w, wv.y, acc[3][1]);
      acc[3][2] = fmaf(av.w, wv.z, acc[3][2]); acc[3][3] = fmaf(av.w, wv.w, acc[3][3]);
    }
    __syncthreads();
  }
#pragma unroll
  for (int i = 0; i < 4; ++i) {
    int r = r0 + (my << 2) + i;
    int t = r >> 6, b = r & 63;
    float* orow = preds + (size_t)b * (TDEC * VOC) + (size_t)t * VOC;
#pragma unroll
    for (int j = 0; j < 4; ++j) {
      int col = n0 + (nx << 2) + j;
      if (col < VOC) orow[col] = acc[i][j] + b_fc[col];
    }
  }
}

extern "C" void kernel_launch(void* const* d_in, const int* in_sizes, int n_in,
                              void* d_out, int out_size, void* d_ws, size_t ws_size,
                              hipStream_t stream) {
  const float* enc = (const float*)d_in[0];
  const int* captions = (const int*)d_in[1];
  const float* W_enc_att = (const float*)d_in[2];
  const float* b_enc_att = (const float*)d_in[3];
  const float* W_dec_att = (const float*)d_in[4];
  const float* b_dec_att = (const float*)d_in[5];
  const float* W_full = (const float*)d_in[6];
  const float* embedding = (const float*)d_in[8];
  const float* W_ih = (const float*)d_in[9];
  const float* W_hh = (const float*)d_in[10];
  const float* b_ih = (const float*)d_in[11];
  const float* b_hh = (const float*)d_in[12];
  const float* W_init_h = (const float*)d_in[13];
  const float* b_init_h = (const float*)d_in[14];
  const float* W_init_c = (const float*)d_in[15];
  const float* b_init_c = (const float*)d_in[16];
  const float* W_f_beta = (const float*)d_in[17];
  const float* b_f_beta = (const float*)d_in[18];
  const float* W_fc = (const float*)d_in[19];
  const float* b_fc = (const float*)d_in[20];

  float* out = (float*)d_out;
  float* preds = out;                             // 64*20*9490 = 12,147,200
  float* alphas = out + (size_t)BB * TDEC * VOC;  // 64*20*196
  // att1 (64*196*512 = 6,422,528 floats) aliases the preds region: it is dead
  // before fc_kernel writes preds. Keeps workspace tiny (~5 MB).
  float* att1 = preds;

  float* ws = (float*)d_ws;
  float* c = ws;                                // 32768
  float* F2 = c + BB * DECD;                    // 64*2560 = 163840
  float* scores = F2 + BB * F2STR;              // 12544
  float* lstm_in = scores + BB * PP;            // 163840
  float* gates = lstm_in + BB * (EMBD + ENCD);  // 131072
  float* mean = gates + BB * 4 * DECD;          // 131072
  float* Hbuf = mean + BB * ENCD;               // 21*32768 = 688128
  // total = 1,323,264 floats = 5.3 MB

  hipMemsetAsync(c, 0, (size_t)BB * DECD * 4, stream);
  hipMemsetAsync(Hbuf, 0, (size_t)BB * DECD * 4, stream);  // h0 accumulator

  mean_kernel<<<BB * ENCD / 4, 256, 0, stream>>>(enc, mean);
  gemm64_atomic<<<dim3(DECD / 64, 4), 256, 0, stream>>>(mean, ENCD, W_init_h, DECD,
                                                        Hbuf, DECD, b_init_h, 512);
  gemm64_atomic<<<dim3(DECD / 64, 4), 256, 0, stream>>>(mean, ENCD, W_init_c, DECD, c,
                                                        DECD, b_init_c, 512);
  att1_kernel<<<dim3(ATTD / 64, 4, BB), 256, 0, stream>>>(enc, W_enc_att, b_enc_att,
                                                          att1);
  emb0_kernel<<<BB * EMBD / 256, 256, 0, stream>>>(captions, embedding, lstm_in);

  for (int t = 0; t < TDEC; ++t) {
    const float* hprev = Hbuf + (size_t)t * BB * DECD;
    float* hnext = Hbuf + (size_t)(t + 1) * BB * DECD;
    hgemm_step<<<(ATTD + ENCD + 4 * DECD) / 32, 256, 0, stream>>>(
        hprev, W_dec_att, b_dec_att, W_f_beta, b_f_beta, W_hh, b_ih, b_hh, F2, gates);
    score_kernel<<<BB * PP / 4, 256, 0, stream>>>(att1, F2, W_full, scores);
    awe_softmax_kernel<<<dim3(ENCD / 256, BB), 256, 0, stream>>>(scores, F2, enc,
                                                                 alphas, lstm_in, t);
    gates_gemm<<<dim3(4 * DECD / 32, 5), 256, 0, stream>>>(lstm_in, W_ih, gates);
    lstm_kernel<<<BB * DECD / 256, 256, 0, stream>>>(gates, c, hnext, captions,
                                                     embedding, lstm_in, t + 1);
  }
  fc_kernel<<<dim3((VOC + 63) / 64, TDEC * BB / 64), 256, 0, stream>>>(
      Hbuf + BB * DECD, W_fc, b_fc, preds);
}

// Round 5
// 3985.467 us; speedup vs baseline: 1.6769x; 1.0259x over previous
//
#include <hip/hip_runtime.h>
#include <cstddef>

#define BB 64
#define PP 196
#define ENCD 2048
#define DECD 512
#define ATTD 512
#define EMBD 512
#define VOC 9490
#define TDEC 20
#define F2STR 2560  // F2 row: [att2 512 | gate 2048]

__device__ __forceinline__ float sigmoidf_(float x) { return 1.f / (1.f + __expf(-x)); }

__device__ __forceinline__ void fma8(float (&acc)[4][8], float4 av, float4 w0, float4 w1) {
  acc[0][0] = fmaf(av.x, w0.x, acc[0][0]); acc[0][1] = fmaf(av.x, w0.y, acc[0][1]);
  acc[0][2] = fmaf(av.x, w0.z, acc[0][2]); acc[0][3] = fmaf(av.x, w0.w, acc[0][3]);
  acc[0][4] = fmaf(av.x, w1.x, acc[0][4]); acc[0][5] = fmaf(av.x, w1.y, acc[0][5]);
  acc[0][6] = fmaf(av.x, w1.z, acc[0][6]); acc[0][7] = fmaf(av.x, w1.w, acc[0][7]);
  acc[1][0] = fmaf(av.y, w0.x, acc[1][0]); acc[1][1] = fmaf(av.y, w0.y, acc[1][1]);
  acc[1][2] = fmaf(av.y, w0.z, acc[1][2]); acc[1][3] = fmaf(av.y, w0.w, acc[1][3]);
  acc[1][4] = fmaf(av.y, w1.x, acc[1][4]); acc[1][5] = fmaf(av.y, w1.y, acc[1][5]);
  acc[1][6] = fmaf(av.y, w1.z, acc[1][6]); acc[1][7] = fmaf(av.y, w1.w, acc[1][7]);
  acc[2][0] = fmaf(av.z, w0.x, acc[2][0]); acc[2][1] = fmaf(av.z, w0.y, acc[2][1]);
  acc[2][2] = fmaf(av.z, w0.z, acc[2][2]); acc[2][3] = fmaf(av.z, w0.w, acc[2][3]);
  acc[2][4] = fmaf(av.z, w1.x, acc[2][4]); acc[2][5] = fmaf(av.z, w1.y, acc[2][5]);
  acc[2][6] = fmaf(av.z, w1.z, acc[2][6]); acc[2][7] = fmaf(av.z, w1.w, acc[2][7]);
  acc[3][0] = fmaf(av.w, w0.x, acc[3][0]); acc[3][1] = fmaf(av.w, w0.y, acc[3][1]);
  acc[3][2] = fmaf(av.w, w0.z, acc[3][2]); acc[3][3] = fmaf(av.w, w0.w, acc[3][3]);
  acc[3][4] = fmaf(av.w, w1.x, acc[3][4]); acc[3][5] = fmaf(av.w, w1.y, acc[3][5]);
  acc[3][6] = fmaf(av.w, w1.z, acc[3][6]); acc[3][7] = fmaf(av.w, w1.w, acc[3][7]);
}

// ---------------- mean over P of encoder_out rows (B*ENC rows of 196) -------
__global__ __launch_bounds__(256) void mean_kernel(const float* __restrict__ enc,
                                                   float* __restrict__ mean) {
  int row = blockIdx.x * 4 + (threadIdx.x >> 6);
  int lane = threadIdx.x & 63;
  const float* r = enc + (size_t)row * PP;
  float v = r[lane] + r[lane + 64] + r[lane + 128];
  if (lane < 4) v += r[lane + 192];
#pragma unroll
  for (int off = 32; off; off >>= 1) v += __shfl_down(v, off);
  if (lane == 0) mean[row] = v * (1.f / 196.f);
}

// ---------------- 64-row x 64-col GEMM, k-split atomic (init h0/c0) ---------
__global__ __launch_bounds__(256) void gemm64_atomic(
    const float* __restrict__ A, int lda, const float* __restrict__ W, int ldw,
    float* __restrict__ C, int ldc, const float* __restrict__ bias0, int kchunk) {
  __shared__ __align__(16) float As[16][68];
  int tid = threadIdx.x;
  int my = tid >> 4, nx = tid & 15;
  int am = tid >> 2, ak = (tid & 3) << 2;
  int n0 = blockIdx.x * 64;
  int k0s = blockIdx.y * kchunk, k0e = k0s + kchunk;
  float acc[4][4] = {};
  for (int k0 = k0s; k0 < k0e; k0 += 16) {
    float4 a4 = *(const float4*)(A + (size_t)am * lda + k0 + ak);
    As[ak + 0][am] = a4.x;
    As[ak + 1][am] = a4.y;
    As[ak + 2][am] = a4.z;
    As[ak + 3][am] = a4.w;
    __syncthreads();
    const float* wp = W + (size_t)k0 * ldw + n0 + (nx << 2);
#pragma unroll
    for (int kk = 0; kk < 16; ++kk) {
      float4 av = *(const float4*)&As[kk][my << 2];
      float4 wv = *(const float4*)(wp + (size_t)kk * ldw);
      acc[0][0] = fmaf(av.x, wv.x, acc[0][0]); acc[0][1] = fmaf(av.x, wv.y, acc[0][1]);
      acc[0][2] = fmaf(av.x, wv.z, acc[0][2]); acc[0][3] = fmaf(av.x, wv.w, acc[0][3]);
      acc[1][0] = fmaf(av.y, wv.x, acc[1][0]); acc[1][1] = fmaf(av.y, wv.y, acc[1][1]);
      acc[1][2] = fmaf(av.y, wv.z, acc[1][2]); acc[1][3] = fmaf(av.y, wv.w, acc[1][3]);
      acc[2][0] = fmaf(av.z, wv.x, acc[2][0]); acc[2][1] = fmaf(av.z, wv.y, acc[2][1]);
      acc[2][2] = fmaf(av.z, wv.z, acc[2][2]); acc[2][3] = fmaf(av.z, wv.w, acc[2][3]);
      acc[3][0] = fmaf(av.w, wv.x, acc[3][0]); acc[3][1] = fmaf(av.w, wv.y, acc[3][1]);
      acc[3][2] = fmaf(av.w, wv.z, acc[3][2]); acc[3][3] = fmaf(av.w, wv.w, acc[3][3]);
    }
    __syncthreads();
  }
  bool first = (blockIdx.y == 0);
#pragma unroll
  for (int i = 0; i < 4; ++i) {
    int row = (my << 2) + i;
#pragma unroll
    for (int j = 0; j < 4; ++j) {
      int col = n0 + (nx << 2) + j;
      float v = acc[i][j];
      if (first && bias0) v += bias0[col];
      atomicAdd(&C[(size_t)row * ldc + col], v);
    }
  }
}

// ------- att1 = enc(b,p,e) @ W_enc_att + b_enc_att ; 64p x 128a tiles -------
__global__ __launch_bounds__(256) void att1_kernel(const float* __restrict__ enc,
                                                   const float* __restrict__ Wea,
                                                   const float* __restrict__ bea,
                                                   float* __restrict__ att1) {
  __shared__ __align__(16) float As[16][68];
  int tid = threadIdx.x;
  int my = tid >> 4, nx = tid & 15;  // 4 p-rows, 8 a-cols (two float4 halves)
  int kr = tid >> 4, pg = (tid & 15) << 2;
  int a0 = blockIdx.x * 128;
  int p0 = blockIdx.y * 64;
  int b = blockIdx.z;
  const float* encb = enc + (size_t)b * ENCD * PP;
  float acc[4][8] = {};
  for (int k0 = 0; k0 < ENCD; k0 += 16) {
    float4 v = make_float4(0.f, 0.f, 0.f, 0.f);
    if (p0 + pg <= 192) v = *(const float4*)(encb + (size_t)(k0 + kr) * PP + p0 + pg);
    *(float4*)&As[kr][pg] = v;
    __syncthreads();
    const float* wp = Wea + (size_t)k0 * ATTD + a0 + (nx << 2);
#pragma unroll
    for (int kk = 0; kk < 16; ++kk) {
      float4 av = *(const float4*)&As[kk][my << 2];
      float4 w0 = *(const float4*)(wp + (size_t)kk * ATTD);
      float4 w1 = *(const float4*)(wp + (size_t)kk * ATTD + 64);
      fma8(acc, av, w0, w1);
    }
    __syncthreads();
  }
#pragma unroll
  for (int i = 0; i < 4; ++i) {
    int p = p0 + (my << 2) + i;
    if (p < PP) {
      float* orow = att1 + ((size_t)b * PP + p) * ATTD;
#pragma unroll
      for (int j = 0; j < 4; ++j) {
        int c0 = a0 + (nx << 2) + j;
        int c1 = c0 + 64;
        orow[c0] = acc[i][j] + bea[c0];
        orow[c1] = acc[i][j + 4] + bea[c1];
      }
    }
  }
}

// -- per-step h-GEMM: h@[Wdec -> F2 | Wfbeta(sigma) -> F2 | Whh+bih+bhh -> gates]
__global__ __launch_bounds__(256) void hgemm_step(
    const float* __restrict__ hprev, const float* __restrict__ Wdec,
    const float* __restrict__ bdec, const float* __restrict__ Wfb,
    const float* __restrict__ bfb, const float* __restrict__ Whh,
    const float* __restrict__ b_ih, const float* __restrict__ b_hh,
    float* __restrict__ F2, float* __restrict__ gates) {
  int cg0 = blockIdx.x * 32;  // [0, 4608)
  const float* W;
  const float* bias;
  const float* bias2 = nullptr;
  float* outp;
  int ostr, wcol, act, ldw, ocol;
  if (cg0 < ATTD) {
    W = Wdec; bias = bdec; wcol = cg0; act = 0; ldw = ATTD;
    outp = F2; ostr = F2STR; ocol = cg0;
  } else if (cg0 < ATTD + ENCD) {
    W = Wfb; bias = bfb; wcol = cg0 - ATTD; act = 1; ldw = ENCD;
    outp = F2; ostr = F2STR; ocol = cg0;
  } else {
    W = Whh; bias = b_ih; bias2 = b_hh; wcol = cg0 - (ATTD + ENCD); act = 0;
    ldw = 4 * DECD; outp = gates; ostr = 4 * DECD; ocol = wcol;
  }
  __shared__ __align__(16) float As[16][68];
  int tid = threadIdx.x;
  int my = tid >> 3, nx = tid & 7;  // 2 rows x 4 cols per thread
  int am = tid >> 2, ak = (tid & 3) << 2;
  float acc[2][4] = {};
  for (int k0 = 0; k0 < DECD; k0 += 16) {
    float4 a4 = *(const float4*)(hprev + (size_t)am * DECD + k0 + ak);
    As[ak + 0][am] = a4.x;
    As[ak + 1][am] = a4.y;
    As[ak + 2][am] = a4.z;
    As[ak + 3][am] = a4.w;
    __syncthreads();
    const float* wp = W + (size_t)k0 * ldw + wcol + (nx << 2);
#pragma unroll
    for (int kk = 0; kk < 16; ++kk) {
      float2 av = *(const float2*)&As[kk][my << 1];
      float4 wv = *(const float4*)(wp + (size_t)kk * ldw);
      acc[0][0] = fmaf(av.x, wv.x, acc[0][0]); acc[0][1] = fmaf(av.x, wv.y, acc[0][1]);
      acc[0][2] = fmaf(av.x, wv.z, acc[0][2]); acc[0][3] = fmaf(av.x, wv.w, acc[0][3]);
      acc[1][0] = fmaf(av.y, wv.x, acc[1][0]); acc[1][1] = fmaf(av.y, wv.y, acc[1][1]);
      acc[1][2] = fmaf(av.y, wv.z, acc[1][2]); acc[1][3] = fmaf(av.y, wv.w, acc[1][3]);
    }
    __syncthreads();
  }
#pragma unroll
  for (int i = 0; i < 2; ++i) {
    int row = (my << 1) + i;
#pragma unroll
    for (int j = 0; j < 4; ++j) {
      int cl = (nx << 2) + j;
      float v = acc[i][j] + bias[wcol + cl];
      if (bias2) v += bias2[wcol + cl];
      if (act) v = sigmoidf_(v);
      outp[(size_t)row * ostr + ocol + cl] = v;
    }
  }
}

// -------- score[b,p] = sum_a relu(att1+att2)*wf : one wave per (b,p) --------
__global__ __launch_bounds__(256) void score_kernel(const float* __restrict__ att1,
                                                    const float* __restrict__ F2,
                                                    const float* __restrict__ W_full,
                                                    float* __restrict__ scores) {
  int w = blockIdx.x * 4 + (threadIdx.x >> 6);  // [0, 12544)
  int lane = threadIdx.x & 63;
  int b = w / PP, p = w - b * PP;
  const float4* row = (const float4*)(att1 + ((size_t)b * PP + p) * ATTD) + (lane << 1);
  const float4* a2 = (const float4*)(F2 + (size_t)b * F2STR) + (lane << 1);
  const float4* w4 = (const float4*)W_full + (lane << 1);
  float acc = 0.f;
#pragma unroll
  for (int i = 0; i < 2; ++i) {
    float4 v = row[i], a = a2[i], wf = w4[i];
    acc = fmaf(fmaxf(v.x + a.x, 0.f), wf.x, acc);
    acc = fmaf(fmaxf(v.y + a.y, 0.f), wf.y, acc);
    acc = fmaf(fmaxf(v.z + a.z, 0.f), wf.z, acc);
    acc = fmaf(fmaxf(v.w + a.w, 0.f), wf.w, acc);
  }
#pragma unroll
  for (int off = 32; off; off >>= 1) acc += __shfl_down(acc, off);
  if (lane == 0) scores[b * PP + p] = acc;
}

// -------- softmax(196) per block + gated awe for a 256-wide e-slice ---------
__global__ __launch_bounds__(256) void awe_softmax_kernel(
    const float* __restrict__ scores, const float* __restrict__ F2,
    const float* __restrict__ enc, float* __restrict__ alphas_out,
    float* __restrict__ lstm_in, int t) {
  int b = blockIdx.y, et = blockIdx.x, tid = threadIdx.x;
  __shared__ __align__(16) float al[256];
  __shared__ float sc[256];
  __shared__ float red[256];
  float s = (tid < PP) ? scores[b * PP + tid] : -1e30f;
  sc[tid] = s;
  __syncthreads();
  for (int off = 128; off; off >>= 1) {
    if (tid < off) sc[tid] = fmaxf(sc[tid], sc[tid + off]);
    __syncthreads();
  }
  float e = (tid < PP) ? __expf(s - sc[0]) : 0.f;
  red[tid] = e;
  __syncthreads();
  for (int off = 128; off; off >>= 1) {
    if (tid < off) red[tid] += red[tid + off];
    __syncthreads();
  }
  float a = e * (1.f / red[0]);
  al[tid] = a;
  if (et == 0 && tid < PP)
    alphas_out[(size_t)b * (TDEC * PP) + (size_t)t * PP + tid] = a;
  __syncthreads();
  int e0 = et * 256 + tid;
  const float4* row = (const float4*)(enc + ((size_t)b * ENCD + e0) * PP);
  const float4* al4 = (const float4*)al;
  float acc = 0.f;
#pragma unroll 7
  for (int i = 0; i < PP / 4; ++i) {
    float4 v = row[i], aa = al4[i];
    acc = fmaf(v.x, aa.x, acc);
    acc = fmaf(v.y, aa.y, acc);
    acc = fmaf(v.z, aa.z, acc);
    acc = fmaf(v.w, aa.w, acc);
  }
  float gate = F2[(size_t)b * F2STR + ATTD + e0];
  lstm_in[(size_t)b * (EMBD + ENCD) + EMBD + e0] = gate * acc;
}

// -------- gates += lstm_in @ W_ih  (k-split atomic; biases+hh already there) -
__global__ __launch_bounds__(256) void gates_gemm(const float* __restrict__ A,
                                                  const float* __restrict__ W_ih,
                                                  float* __restrict__ gates) {
  const int K = EMBD + ENCD, N = 4 * DECD, kchunk = 512;
  __shared__ __align__(16) float As[16][68];
  int tid = threadIdx.x;
  int my = tid >> 3, nx = tid & 7;
  int am = tid >> 2, ak = (tid & 3) << 2;
  int n0 = blockIdx.x * 32;
  int k0s = blockIdx.y * kchunk, k0e = k0s + kchunk;
  float acc[2][4] = {};
  for (int k0 = k0s; k0 < k0e; k0 += 16) {
    float4 a4 = *(const float4*)(A + (size_t)am * K + k0 + ak);
    As[ak + 0][am] = a4.x;
    As[ak + 1][am] = a4.y;
    As[ak + 2][am] = a4.z;
    As[ak + 3][am] = a4.w;
    __syncthreads();
    const float* wp = W_ih + (size_t)k0 * N + n0 + (nx << 2);
#pragma unroll
    for (int kk = 0; kk < 16; ++kk) {
      float2 av = *(const float2*)&As[kk][my << 1];
      float4 wv = *(const float4*)(wp + (size_t)kk * N);
      acc[0][0] = fmaf(av.x, wv.x, acc[0][0]); acc[0][1] = fmaf(av.x, wv.y, acc[0][1]);
      acc[0][2] = fmaf(av.x, wv.z, acc[0][2]); acc[0][3] = fmaf(av.x, wv.w, acc[0][3]);
      acc[1][0] = fmaf(av.y, wv.x, acc[1][0]); acc[1][1] = fmaf(av.y, wv.y, acc[1][1]);
      acc[1][2] = fmaf(av.y, wv.z, acc[1][2]); acc[1][3] = fmaf(av.y, wv.w, acc[1][3]);
    }
    __syncthreads();
  }
#pragma unroll
  for (int i = 0; i < 2; ++i) {
    int row = (my << 1) + i;
#pragma unroll
    for (int j = 0; j < 4; ++j) {
      int col = n0 + (nx << 2) + j;
      atomicAdd(&gates[(size_t)row * N + col], acc[i][j]);
    }
  }
}

// ---- LSTM pointwise -> h into Hbuf slot; gathers next-step embedding -------
__global__ __launch_bounds__(256) void lstm_kernel(const float* __restrict__ gates,
                                                   float* __restrict__ c,
                                                   float* __restrict__ hout,
                                                   const int* __restrict__ captions,
                                                   const float* __restrict__ embedding,
                                                   float* __restrict__ lstm_in, int tn) {
  int idx = blockIdx.x * 256 + threadIdx.x;  // 0..32767
  int b = idx >> 9, d = idx & 511;
  const float* g = gates + (size_t)b * 2048;
  float gi = g[d], gf = g[d + 512], gg = g[d + 1024], go = g[d + 1536];
  float iv = sigmoidf_(gi);
  float fv = sigmoidf_(gf);
  float ov = sigmoidf_(go);
  float gv = tanhf(gg);
  float cn = fv * c[idx] + iv * gv;
  c[idx] = cn;
  hout[idx] = ov * tanhf(cn);
  int tok = captions[b * 21 + tn];
  lstm_in[(size_t)b * (EMBD + ENCD) + d] = embedding[(size_t)tok * EMBD + d];
}

// ---------------- t=0 embedding gather --------------------------------------
__global__ __launch_bounds__(256) void emb0_kernel(const int* __restrict__ captions,
                                                   const float* __restrict__ embedding,
                                                   float* __restrict__ lstm_in) {
  int idx = blockIdx.x * 256 + threadIdx.x;
  int b = idx >> 9, d = idx & 511;
  int tok = captions[b * 21];
  lstm_in[(size_t)b * (EMBD + ENCD) + d] = embedding[(size_t)tok * EMBD + d];
}

// ------- preds = Hfc(1280x512) @ W_fc + b_fc ; 64r x 128c tiles -------------
// grid (20 row-tiles, 75 col-tiles): consecutive blocks share one W tile.
// Tail col-tile (n0+128 > VOC) takes a guarded scalar path (block-uniform).
__global__ __launch_bounds__(256) void fc_kernel(const float* __restrict__ Hfc,
                                                 const float* __restrict__ W_fc,
                                                 const float* __restrict__ b_fc,
                                                 float* __restrict__ preds) {
  __shared__ __align__(16) float As[16][68];
  int tid = threadIdx.x;
  int my = tid >> 4, nx = tid & 15;  // 4 rows, 8 cols (two float4 halves)
  int am = tid >> 2, ak = (tid & 3) << 2;
  int r0 = blockIdx.x * 64;
  int n0 = blockIdx.y * 128;
  const float* A = Hfc + (size_t)r0 * DECD;
  int cb = n0 + (nx << 2);
  bool full = (n0 + 128 <= VOC);
  float acc[4][8] = {};
  for (int k0 = 0; k0 < DECD; k0 += 16) {
    float4 a4 = *(const float4*)(A + (size_t)am * DECD + k0 + ak);
    As[ak + 0][am] = a4.x;
    As[ak + 1][am] = a4.y;
    As[ak + 2][am] = a4.z;
    As[ak + 3][am] = a4.w;
    __syncthreads();
    const float* wrow = W_fc + (size_t)k0 * VOC;
    if (full) {
#pragma unroll
      for (int kk = 0; kk < 16; ++kk) {
        float4 av = *(const float4*)&As[kk][my << 2];
        float4 w0 = *(const float4*)(wrow + cb);
        float4 w1 = *(const float4*)(wrow + cb + 64);
        wrow += VOC;
        fma8(acc, av, w0, w1);
      }
    } else {
#pragma unroll
      for (int kk = 0; kk < 16; ++kk) {
        float4 av = *(const float4*)&As[kk][my << 2];
        float4 w0, w1;
        w0.x = (cb + 0 < VOC) ? wrow[cb + 0] : 0.f;
        w0.y = (cb + 1 < VOC) ? wrow[cb + 1] : 0.f;
        w0.z = (cb + 2 < VOC) ? wrow[cb + 2] : 0.f;
        w0.w = (cb + 3 < VOC) ? wrow[cb + 3] : 0.f;
        w1.x = (cb + 64 < VOC) ? wrow[cb + 64] : 0.f;
        w1.y = (cb + 65 < VOC) ? wrow[cb + 65] : 0.f;
        w1.z = (cb + 66 < VOC) ? wrow[cb + 66] : 0.f;
        w1.w = (cb + 67 < VOC) ? wrow[cb + 67] : 0.f;
        wrow += VOC;
        fma8(acc, av, w0, w1);
      }
    }
    __syncthreads();
  }
#pragma unroll
  for (int i = 0; i < 4; ++i) {
    int r = r0 + (my << 2) + i;
    int t = r >> 6, b = r & 63;
    float* orow = preds + (size_t)b * (TDEC * VOC) + (size_t)t * VOC;
#pragma unroll
    for (int j = 0; j < 4; ++j) {
      int colA = cb + j;
      int colB = cb + 64 + j;
      if (colA < VOC) orow[colA] = acc[i][j] + b_fc[colA];
      if (colB < VOC) orow[colB] = acc[i][j + 4] + b_fc[colB];
    }
  }
}

extern "C" void kernel_launch(void* const* d_in, const int* in_sizes, int n_in,
                              void* d_out, int out_size, void* d_ws, size_t ws_size,
                              hipStream_t stream) {
  const float* enc = (const float*)d_in[0];
  const int* captions = (const int*)d_in[1];
  const float* W_enc_att = (const float*)d_in[2];
  const float* b_enc_att = (const float*)d_in[3];
  const float* W_dec_att = (const float*)d_in[4];
  const float* b_dec_att = (const float*)d_in[5];
  const float* W_full = (const float*)d_in[6];
  const float* embedding = (const float*)d_in[8];
  const float* W_ih = (const float*)d_in[9];
  const float* W_hh = (const float*)d_in[10];
  const float* b_ih = (const float*)d_in[11];
  const float* b_hh = (const float*)d_in[12];
  const float* W_init_h = (const float*)d_in[13];
  const float* b_init_h = (const float*)d_in[14];
  const float* W_init_c = (const float*)d_in[15];
  const float* b_init_c = (const float*)d_in[16];
  const float* W_f_beta = (const float*)d_in[17];
  const float* b_f_beta = (const float*)d_in[18];
  const float* W_fc = (const float*)d_in[19];
  const float* b_fc = (const float*)d_in[20];

  float* out = (float*)d_out;
  float* preds = out;                             // 64*20*9490
  float* alphas = out + (size_t)BB * TDEC * VOC;  // 64*20*196
  // att1 aliases the preds region: dead before fc_kernel writes preds.
  float* att1 = preds;

  float* ws = (float*)d_ws;
  float* c = ws;                                // 32768
  float* F2 = c + BB * DECD;                    // 163840
  float* scores = F2 + BB * F2STR;              // 12544
  float* lstm_in = scores + BB * PP;            // 163840
  float* gates = lstm_in + BB * (EMBD + ENCD);  // 131072
  float* mean = gates + BB * 4 * DECD;          // 131072
  float* Hbuf = mean + BB * ENCD;               // 688128
  // total ~5.3 MB

  hipMemsetAsync(c, 0, (size_t)BB * DECD * 4, stream);
  hipMemsetAsync(Hbuf, 0, (size_t)BB * DECD * 4, stream);  // h0 accumulator

  mean_kernel<<<BB * ENCD / 4, 256, 0, stream>>>(enc, mean);
  gemm64_atomic<<<dim3(DECD / 64, 4), 256, 0, stream>>>(mean, ENCD, W_init_h, DECD,
                                                        Hbuf, DECD, b_init_h, 512);
  gemm64_atomic<<<dim3(DECD / 64, 4), 256, 0, stream>>>(mean, ENCD, W_init_c, DECD, c,
                                                        DECD, b_init_c, 512);
  att1_kernel<<<dim3(ATTD / 128, 4, BB), 256, 0, stream>>>(enc, W_enc_att, b_enc_att,
                                                           att1);
  emb0_kernel<<<BB * EMBD / 256, 256, 0, stream>>>(captions, embedding, lstm_in);

  for (int t = 0; t < TDEC; ++t) {
    const float* hprev = Hbuf + (size_t)t * BB * DECD;
    float* hnext = Hbuf + (size_t)(t + 1) * BB * DECD;
    hgemm_step<<<(ATTD + ENCD + 4 * DECD) / 32, 256, 0, stream>>>(
        hprev, W_dec_att, b_dec_att, W_f_beta, b_f_beta, W_hh, b_ih, b_hh, F2, gates);
    score_kernel<<<BB * PP / 4, 256, 0, stream>>>(att1, F2, W_full, scores);
    awe_softmax_kernel<<<dim3(ENCD / 256, BB), 256, 0, stream>>>(scores, F2, enc,
                                                                 alphas, lstm_in, t);
    gates_gemm<<<dim3(4 * DECD / 32, 5), 256, 0, stream>>>(lstm_in, W_ih, gates);
    lstm_kernel<<<BB * DECD / 256, 256, 0, stream>>>(gates, c, hnext, captions,
                                                     embedding, lstm_in, t + 1);
  }
  fc_kernel<<<dim3(TDEC * BB / 64, (VOC + 127) / 128), 256, 0, stream>>>(
      Hbuf + BB * DECD, W_fc, b_fc, preds);
}